// Round 2
// baseline (361.703 us; speedup 1.0000x reference)
//
#include <hip/hip_runtime.h>

#define B_ 64
#define C_ 32
#define H_ 16
#define W_ 16
#define V_ 4096
#define NELEM_ (B_*C_*H_*W_)   // 524288

// ---------------------------------------------------------------- utilities

__device__ __forceinline__ float keys_cubic(float x) {
  // Keys cubic kernel, a = -0.5 (jax.image.resize 'cubic'), x >= 0
  if (x >= 2.f) return 0.f;
  if (x >= 1.f) return ((-0.5f*x + 2.5f)*x - 4.f)*x + 2.f;
  return (1.5f*x - 2.5f)*x*x + 1.f;
}

// ---------------------------------------------------------------- kernels

__global__ void init_kernel(const float* __restrict__ f, float* __restrict__ f_rest,
                            float* __restrict__ f_hat, float* __restrict__ loss_part) {
  int i = blockIdx.x*blockDim.x + threadIdx.x;
  if (i < NELEM_) { f_rest[i] = f[i]; f_hat[i] = 0.f; }
  if (i < 5*256) loss_part[i] = 0.f;
}

__global__ void esq_kernel(const float* __restrict__ emb, float* __restrict__ e_sq) {
  int v = blockIdx.x*blockDim.x + threadIdx.x;
  if (v >= V_) return;
  const float4* p = (const float4*)(emb + (size_t)v*32);
  float s = 0.f;
#pragma unroll
  for (int i = 0; i < 8; ++i) { float4 q = p[i]; s += q.x*q.x + q.y*q.y + q.z*q.z + q.w*q.w; }
  e_sq[v] = s;
}

// pool f_rest [B,C,16,16] -> z [N, C], N = B*pn*pn, position-major (b, y, x)
__global__ void pool_kernel(const float* __restrict__ f_rest, float* __restrict__ z,
                            int pn, int k) {
  int t = blockIdx.x*blockDim.x + threadIdx.x;
  int N = B_*pn*pn;
  if (t >= N*C_) return;
  int n = t >> 5, c = t & 31;
  int pn2 = pn*pn;
  int b = n / pn2, rem = n % pn2;
  int y = rem / pn, x = rem % pn;
  const float* base = f_rest + (((size_t)b*C_ + c)*H_ + y*k)*W_ + x*k;
  float s = 0.f;
  for (int ky = 0; ky < k; ++ky)
    for (int kx = 0; kx < k; ++kx)
      s += base[ky*W_ + kx];
  z[(size_t)n*32 + c] = s * (1.f/(float)(k*k));
}

// each thread owns one position, scans a chunk of codes.
// distance mimics the reference association: d = (zz + e_sq[v]) - 2*dot
__global__ void __launch_bounds__(256) argmin_kernel(
    const float* __restrict__ z, const float* __restrict__ emb,
    const float* __restrict__ e_sq, unsigned long long* __restrict__ part,
    int N, int codes_per_chunk) {
  int n = blockIdx.x*blockDim.x + threadIdx.x;
  if (n >= N) return;
  float zb[32];
  const float4* zp = (const float4*)(z + (size_t)n*32);
#pragma unroll
  for (int i = 0; i < 8; ++i) {
    float4 q = zp[i];
    zb[4*i+0]=q.x; zb[4*i+1]=q.y; zb[4*i+2]=q.z; zb[4*i+3]=q.w;
  }
  float zz = 0.f;
#pragma unroll
  for (int i = 0; i < 32; ++i) zz = fmaf(zb[i], zb[i], zz);
  int v0 = blockIdx.y * codes_per_chunk;
  float best_d = 3.4e38f; int best_i = v0;
  for (int v = v0; v < v0 + codes_per_chunk; ++v) {
    const float4* e4 = (const float4*)(emb + (size_t)v*32);   // uniform -> s_load
    float a0=0.f, a1=0.f, a2=0.f, a3=0.f;
#pragma unroll
    for (int i = 0; i < 8; ++i) {
      float4 q = e4[i];
      a0 = fmaf(zb[4*i+0], q.x, a0);
      a1 = fmaf(zb[4*i+1], q.y, a1);
      a2 = fmaf(zb[4*i+2], q.z, a2);
      a3 = fmaf(zb[4*i+3], q.w, a3);
    }
    float dot = (a0+a1)+(a2+a3);
    float d = (zz + e_sq[v]) - 2.f*dot;
    if (d < best_d) { best_d = d; best_i = v; }   // strict < keeps lowest index
  }
  unsigned int bu = __float_as_uint(best_d);
  unsigned int m = bu ^ ((bu >> 31) ? 0xFFFFFFFFu : 0x80000000u);  // order-preserving
  part[(size_t)blockIdx.y * N + n] = ((unsigned long long)m << 32) | (unsigned int)best_i;
}

// fused: argmin-chunk reduce -> gather emb -> bicubic upsample -> conv3x3 blend
// -> f_hat += h, f_rest -= h, loss partial.  grid (64 images, 4 co-groups)
template<int PN>
__global__ void __launch_bounds__(256) upconv_kernel(
    const unsigned long long* __restrict__ part, int nvc,
    const float* __restrict__ emb,
    const float* __restrict__ phi_w,   // [32][32][3][3] (already offset by phi idx)
    const float* __restrict__ phi_b,   // [32]
    const float* __restrict__ f,
    float* __restrict__ f_hat,
    float* __restrict__ f_rest,
    float* __restrict__ loss_part)     // offset to si*256
{
  constexpr int PN2 = PN*PN;
  constexpr int NPOS = B_*PN2;
  const int b = blockIdx.x;
  const int cg = blockIdx.y;       // co group: co = cg*8 + (0..7)
  const int tid = threadIdx.x;

  __shared__ int   idx_s[PN2];
  __shared__ float W4[16][4];
  __shared__ int   I0[16];
  __shared__ float wlds[8*32*9];
  __shared__ float tmp_s[(PN < 16) ? C_*PN*16 : 1];
  union HupHs { float hup[C_*16*17]; float hs[C_*16*17]; };
  __shared__ HupHs u;   // hs dead before hup is written (barrier between)

  // ---- stage 0: reduce argmin partials for this image's positions
  for (int p = tid; p < PN2; p += 256) {
    int n = b*PN2 + p;
    unsigned long long best = part[n];
    for (int vc = 1; vc < nvc; ++vc) {
      unsigned long long kk = part[(size_t)vc*NPOS + n];
      if (kk < best) best = kk;
    }
    idx_s[p] = (int)(best & 0xFFFFFFFFull);
  }
  // ---- stage W: bicubic weights (separable, 4 taps, renormalized at border)
  if (PN < 16 && tid < 16) {
    float sf = (tid + 0.5f) * ((float)PN/16.f) - 0.5f;
    int i0 = (int)floorf(sf) - 1;
    float w[4]; float tot = 0.f;
#pragma unroll
    for (int t = 0; t < 4; ++t) {
      int i = i0 + t;
      float wv = (i >= 0 && i < PN) ? keys_cubic(fabsf(sf - (float)i)) : 0.f;
      w[t] = wv; tot += wv;
    }
    float r = 1.f/tot;
#pragma unroll
    for (int t = 0; t < 4; ++t) W4[tid][t] = w[t]*r;
    I0[tid] = i0;
  }
  // ---- conv weights for this co-group into LDS
  for (int e = tid; e < 8*32*9; e += 256) wlds[e] = phi_w[cg*(8*32*9) + e];
  __syncthreads();

  // ---- stage B: gather codes
  if (PN < 16) {
    for (int e = tid; e < C_*PN2; e += 256) {
      int c = e / PN2, p = e % PN2;
      u.hs[c*PN2 + p] = emb[(size_t)idx_s[p]*32 + c];
    }
  } else {
    for (int e = tid; e < C_*256; e += 256) {
      int c = e >> 8, p = e & 255;
      int y = p >> 4, x = p & 15;
      u.hup[(c*16 + y)*17 + x] = emb[(size_t)idx_s[p]*32 + c];
    }
  }
  __syncthreads();

  // ---- stage C: separable bicubic upsample PN -> 16
  if (PN < 16) {
    for (int e = tid; e < C_*PN*16; e += 256) {       // x pass
      int jx = e & 15; int rest = e >> 4;
      int iy = rest % PN; int c = rest / PN;
      int i0 = I0[jx];
      float s = 0.f;
#pragma unroll
      for (int t = 0; t < 4; ++t) {
        int ix = i0 + t; int ixc = min(max(ix, 0), PN-1);
        s += W4[jx][t] * u.hs[(c*PN + iy)*PN + ixc];  // w==0 when tap invalid
      }
      tmp_s[(c*PN + iy)*16 + jx] = s;
    }
    __syncthreads();
    for (int e = tid; e < C_*256; e += 256) {         // y pass
      int jx = e & 15; int jy = (e >> 4) & 15; int c = e >> 8;
      int i0 = I0[jy];
      float s = 0.f;
#pragma unroll
      for (int t = 0; t < 4; ++t) {
        int iy = i0 + t; int iyc = min(max(iy, 0), PN-1);
        s += W4[jy][t] * tmp_s[(c*PN + iyc)*16 + jx];
      }
      u.hup[(c*16 + jy)*17 + jx] = s;
    }
    __syncthreads();
  }

  // ---- stage D: conv3x3 (zero pad) + blend + updates
  const int co_l = tid >> 5;            // 0..7
  const int y    = (tid >> 1) & 15;
  const int x0   = (tid & 1) * 8;
  const int co   = cg*8 + co_l;
  float out[8];
  float bias = phi_b[co];
#pragma unroll
  for (int i = 0; i < 8; ++i) out[i] = bias;
  for (int ci = 0; ci < 32; ++ci) {
    float wk[9];
#pragma unroll
    for (int t = 0; t < 9; ++t) wk[t] = wlds[(co_l*32 + ci)*9 + t];
#pragma unroll
    for (int ky = 0; ky < 3; ++ky) {
      int yy = y + ky - 1;
      if (yy < 0 || yy > 15) continue;
      float hrow[10];
#pragma unroll
      for (int dx = 0; dx < 10; ++dx) {
        int xx = x0 - 1 + dx;
        hrow[dx] = (xx < 0 || xx > 15) ? 0.f : u.hup[(ci*16 + yy)*17 + xx];
      }
#pragma unroll
      for (int xi = 0; xi < 8; ++xi) {
        out[xi] = fmaf(wk[ky*3+0], hrow[xi],   out[xi]);
        out[xi] = fmaf(wk[ky*3+1], hrow[xi+1], out[xi]);
        out[xi] = fmaf(wk[ky*3+2], hrow[xi+2], out[xi]);
      }
    }
  }
  float lsum = 0.f;
#pragma unroll
  for (int xi = 0; xi < 8; ++xi) {
    int x = x0 + xi;
    float h = 0.5f*u.hup[(co*16 + y)*17 + x] + 0.5f*out[xi];
    size_t gi = (((size_t)b*C_ + co)*16 + y)*16 + x;
    float fh = f_hat[gi] + h;
    f_hat[gi] = fh;
    f_rest[gi] -= h;
    float dd = fh - f[gi];
    lsum += dd*dd;
  }
  // deterministic block reduction
#pragma unroll
  for (int off = 32; off > 0; off >>= 1) lsum += __shfl_down(lsum, off);
  __shared__ float wsum[4];
  if ((tid & 63) == 0) wsum[tid >> 6] = lsum;
  __syncthreads();
  if (tid == 0) loss_part[blockIdx.y*64 + blockIdx.x] = (wsum[0]+wsum[1])+(wsum[2]+wsum[3]);
}

__global__ void loss_kernel(const float* __restrict__ loss_part, float* __restrict__ out_loss) {
  __shared__ float s[256];
  int t = threadIdx.x;
  float v = 0.f;
#pragma unroll
  for (int i = 0; i < 5; ++i) v += loss_part[i*256 + t];
  s[t] = v;
  __syncthreads();
  for (int off = 128; off > 0; off >>= 1) {
    if (t < off) s[t] += s[t + off];
    __syncthreads();
  }
  // loss = (1/5) * sum_si 1.25 * S_si / NELEM
  if (t == 0) out_loss[0] = s[0] * (1.25f / (5.f * (float)NELEM_));
}

// ---------------------------------------------------------------- launch

extern "C" void kernel_launch(void* const* d_in, const int* in_sizes, int n_in,
                              void* d_out, int out_size, void* d_ws, size_t ws_size,
                              hipStream_t stream) {
  const float* f     = (const float*)d_in[0];
  const float* emb   = (const float*)d_in[1];
  const float* phi_w = (const float*)d_in[2];   // [4][32][32][3][3]
  const float* phi_b = (const float*)d_in[3];   // [4][32]
  float* f_hat    = (float*)d_out;              // [524288]
  float* out_loss = f_hat + NELEM_;             // [1]

  char* ws = (char*)d_ws;
  float* f_rest = (float*)ws;                                         // 2 MB
  float* z      = (float*)(ws + (size_t)NELEM_*4);                    // 2 MB
  unsigned long long* part = (unsigned long long*)(ws + (size_t)NELEM_*8); // 2 MB
  float* e_sq      = (float*)(ws + (size_t)NELEM_*8 + (size_t)262144*8);
  float* loss_part = e_sq + V_;                                       // 5*256 floats

  init_kernel<<<(NELEM_+255)/256, 256, 0, stream>>>(f, f_rest, f_hat, loss_part);
  esq_kernel<<<V_/256, 256, 0, stream>>>(emb, e_sq);

  const int PNs[5] = {1,2,4,8,16};
  // PHI_IDX from exact float64 replay of np.linspace + np.argmin:
  // ticks = [0.08333333333333333, 0.36111111111111108, 0.63888888888888884, 0.91666666666666663]
  // si=2 (s=0.5): |0.5-ticks[1]|=0.13888888888888892 > |ticks[2]-0.5|=0.13888888888888884 -> 2
  const int PHI[5] = {0,1,2,2,3};
  const int VCH[5] = {64,64,32,16,16};

  for (int si = 0; si < 5; ++si) {
    int pn = PNs[si], k = 16/pn, N = B_*pn*pn;
    pool_kernel<<<(N*C_ + 255)/256, 256, 0, stream>>>(f_rest, z, pn, k);
    dim3 ag((N + 255)/256, VCH[si]);
    argmin_kernel<<<ag, 256, 0, stream>>>(z, emb, e_sq, part, N, V_/VCH[si]);
    const float* pw = phi_w + (size_t)PHI[si]*32*32*9;
    const float* pb = phi_b + (size_t)PHI[si]*32;
    dim3 cgrid(B_, 4);
    float* lp = loss_part + si*256;
    switch (pn) {
      case 1:  upconv_kernel<1 ><<<cgrid,256,0,stream>>>(part, VCH[si], emb, pw, pb, f, f_hat, f_rest, lp); break;
      case 2:  upconv_kernel<2 ><<<cgrid,256,0,stream>>>(part, VCH[si], emb, pw, pb, f, f_hat, f_rest, lp); break;
      case 4:  upconv_kernel<4 ><<<cgrid,256,0,stream>>>(part, VCH[si], emb, pw, pb, f, f_hat, f_rest, lp); break;
      case 8:  upconv_kernel<8 ><<<cgrid,256,0,stream>>>(part, VCH[si], emb, pw, pb, f, f_hat, f_rest, lp); break;
      case 16: upconv_kernel<16><<<cgrid,256,0,stream>>>(part, VCH[si], emb, pw, pb, f, f_hat, f_rest, lp); break;
    }
  }
  loss_kernel<<<1, 256, 0, stream>>>(loss_part, out_loss);
}

// Round 3
// 270.819 us; speedup vs baseline: 1.3356x; 1.3356x over previous
//
#include <hip/hip_runtime.h>

typedef unsigned long long u64;

#define B_ 64
#define C_ 32
#define H_ 16
#define W_ 16
#define V_ 4096
#define NELEM_ (B_*C_*H_*W_)   // 524288
#define NPOS_TOTAL 21824       // 64*(1+4+16+64+256)

// ---------------------------------------------------------------- utilities

__device__ __forceinline__ float keys_cubic(float x) {
  // Keys cubic kernel, a = -0.5 (jax.image.resize 'cubic'), x >= 0
  if (x >= 2.f) return 0.f;
  if (x >= 1.f) return ((-0.5f*x + 2.5f)*x - 4.f)*x + 2.f;
  return (1.5f*x - 2.5f)*x*x + 1.f;
}

__device__ __forceinline__ u64 pack_key(float d, int idx) {
  unsigned bu = __float_as_uint(d);
  unsigned m = bu ^ ((bu >> 31) ? 0xFFFFFFFFu : 0x80000000u);  // order-preserving
  return ((u64)m << 32) | (unsigned)idx;
}

// ---------------------------------------------------------------- init (+e_sq, +part)

__global__ void init_kernel(const float* __restrict__ f, const float* __restrict__ emb,
                            float* __restrict__ f_rest, float* __restrict__ f_hat,
                            float* __restrict__ e_sq, u64* __restrict__ part,
                            float* __restrict__ loss_part) {
  int i = blockIdx.x*blockDim.x + threadIdx.x;
  if (i < NELEM_) { f_rest[i] = f[i]; f_hat[i] = 0.f; }
  if (i < NPOS_TOTAL) part[i] = ~0ull;
  if (i < 5*256) loss_part[i] = 0.f;
  if (i < V_) {
    const float4* p = (const float4*)(emb + (size_t)i*32);
    float s = 0.f;
#pragma unroll
    for (int j = 0; j < 8; ++j) { float4 q = p[j]; s += q.x*q.x + q.y*q.y + q.z*q.z + q.w*q.w; }
    e_sq[i] = s;
  }
}

// ---------------------------------------------------------------- pool

__global__ void pool_kernel(const float* __restrict__ f_rest, float* __restrict__ z,
                            int pn, int k) {
  int t = blockIdx.x*blockDim.x + threadIdx.x;
  int N = B_*pn*pn;
  if (t >= N*C_) return;
  int n = t >> 5, c = t & 31;
  int pn2 = pn*pn;
  int b = n / pn2, rem = n % pn2;
  int y = rem / pn, x = rem % pn;
  const float* base = f_rest + (((size_t)b*C_ + c)*H_ + y*k)*W_ + x*k;
  float s = 0.f;
  if (k >= 4) {
    const float4* b4 = (const float4*)base;        // 16B-aligned: x*k % 4 == 0
    for (int ky = 0; ky < k; ++ky)
      for (int kx = 0; kx < (k>>2); ++kx) {
        float4 q = b4[ky*4 + kx];                  // row stride = 4 float4
        s += (q.x + q.y) + (q.z + q.w);
      }
  } else if (k == 2) {
    const float2* b2 = (const float2*)base;
    s = (b2[0].x + b2[0].y) + (b2[8].x + b2[8].y); // rows y*k, y*k+1
  } else {
    s = base[0];
  }
  z[(size_t)n*32 + c] = s * (1.f/(float)(k*k));
}

// ---------------------------------------------------------------- argmin (LDS-tiled)

template<int P, int TILE>
__global__ void __launch_bounds__(256) argmin2_kernel(
    const float* __restrict__ z, const float* __restrict__ emb,
    const float* __restrict__ e_sq, u64* __restrict__ part, int cpc) {
  __shared__ float cl[TILE*32];
  __shared__ float es[TILE];
  const int tid = threadIdx.x;
  const int n0 = blockIdx.x*256*P + tid;
  float zb[P][32]; float zz[P];
#pragma unroll
  for (int p = 0; p < P; ++p) {
    const float4* zp = (const float4*)(z + (size_t)(n0 + p*256)*32);
#pragma unroll
    for (int i = 0; i < 8; ++i) {
      float4 q = zp[i];
      zb[p][4*i+0]=q.x; zb[p][4*i+1]=q.y; zb[p][4*i+2]=q.z; zb[p][4*i+3]=q.w;
    }
    float s = 0.f;
#pragma unroll
    for (int i = 0; i < 32; ++i) s = fmaf(zb[p][i], zb[p][i], s);
    zz[p] = s;
  }
  const int v0 = blockIdx.y * cpc;
  float bd[P]; int bi[P];
#pragma unroll
  for (int p = 0; p < P; ++p) { bd[p] = 3.4e38f; bi[p] = 0; }
  for (int t0 = 0; t0 < cpc; t0 += TILE) {
    __syncthreads();
    const float4* src = (const float4*)(emb + (size_t)(v0 + t0)*32);
    for (int e = tid; e < TILE*8; e += 256) ((float4*)cl)[e] = src[e];
    if (tid < TILE) es[tid] = e_sq[v0 + t0 + tid];
    __syncthreads();
    for (int c = 0; c < TILE; ++c) {
      const float4* cp = (const float4*)(cl + c*32);
      float4 q[8];
#pragma unroll
      for (int i = 0; i < 8; ++i) q[i] = cp[i];
      float ev = es[c];
#pragma unroll
      for (int p = 0; p < P; ++p) {
        float a0=0.f, a1=0.f, a2=0.f, a3=0.f;
#pragma unroll
        for (int i = 0; i < 8; ++i) {
          a0 = fmaf(zb[p][4*i+0], q[i].x, a0);
          a1 = fmaf(zb[p][4*i+1], q[i].y, a1);
          a2 = fmaf(zb[p][4*i+2], q[i].z, a2);
          a3 = fmaf(zb[p][4*i+3], q[i].w, a3);
        }
        float dot = (a0+a1)+(a2+a3);
        float d = (zz[p] + ev) - 2.f*dot;
        bool lt = d < bd[p];
        bd[p] = lt ? d : bd[p];
        bi[p] = lt ? (v0 + t0 + c) : bi[p];
      }
    }
  }
#pragma unroll
  for (int p = 0; p < P; ++p)
    atomicMin(part + n0 + p*256, pack_key(bd[p], bi[p]));
}

// si=0 special: N=64 positions, 4 code-subchunks per block
__global__ void __launch_bounds__(256) argmin0_kernel(
    const float* __restrict__ z, const float* __restrict__ emb,
    const float* __restrict__ e_sq, u64* __restrict__ part) {
  __shared__ float cl[64*32];
  __shared__ float es[64];
  const int tid = threadIdx.x;
  const int v0 = blockIdx.x * 64;
  const float4* src = (const float4*)(emb + (size_t)v0*32);
  for (int e = tid; e < 64*8; e += 256) ((float4*)cl)[e] = src[e];
  if (tid < 64) es[tid] = e_sq[v0 + tid];
  __syncthreads();
  const int p = tid & 63, sub = tid >> 6;
  float zb[32];
  const float4* zp = (const float4*)(z + (size_t)p*32);
#pragma unroll
  for (int i = 0; i < 8; ++i) {
    float4 q = zp[i];
    zb[4*i+0]=q.x; zb[4*i+1]=q.y; zb[4*i+2]=q.z; zb[4*i+3]=q.w;
  }
  float zz = 0.f;
#pragma unroll
  for (int i = 0; i < 32; ++i) zz = fmaf(zb[i], zb[i], zz);
  float bd = 3.4e38f; int bi = 0;
  for (int c = sub*16; c < sub*16 + 16; ++c) {
    const float4* cp = (const float4*)(cl + c*32);
    float4 q[8];
#pragma unroll
    for (int i = 0; i < 8; ++i) q[i] = cp[i];
    float a0=0.f, a1=0.f, a2=0.f, a3=0.f;
#pragma unroll
    for (int i = 0; i < 8; ++i) {
      a0 = fmaf(zb[4*i+0], q[i].x, a0);
      a1 = fmaf(zb[4*i+1], q[i].y, a1);
      a2 = fmaf(zb[4*i+2], q[i].z, a2);
      a3 = fmaf(zb[4*i+3], q[i].w, a3);
    }
    float dot = (a0+a1)+(a2+a3);
    float d = (zz + es[c]) - 2.f*dot;
    if (d < bd) { bd = d; bi = v0 + c; }
  }
  atomicMin(part + p, pack_key(bd, bi));
}

// ---------------------------------------------------------------- fused upconv

// grid (64 images, 4 co-groups), 512 threads.
// stages: idx read -> gather -> bicubic upsample -> conv (thread=px, 2 co-subgroups)
template<int PN>
__global__ void __launch_bounds__(512) upconv_kernel(
    const u64* __restrict__ part_s,
    const float* __restrict__ emb,
    const float* __restrict__ phi_w,   // [32][32][3][3] (offset by phi idx)
    const float* __restrict__ phi_b,   // [32]
    const float* __restrict__ f,
    float* __restrict__ f_hat,
    float* __restrict__ f_rest,
    float* __restrict__ loss_part)
{
  constexpr int PN2 = PN*PN;
  const int b = blockIdx.x;
  const int cg = blockIdx.y;
  const int tid = threadIdx.x;

  __shared__ int   idx_s[PN2];
  __shared__ float W4[16][4];
  __shared__ int   I0[16];
  __shared__ float tmp_s[(PN < 16) ? C_*PN*16 : 1];
  union HupHs { float hup[C_*16*18]; float hs[C_*16*18]; };  // hup row: [pad,16,pad]
  __shared__ HupHs u;
  __shared__ float wsum[8];

  for (int p = tid; p < PN2; p += 512)
    idx_s[p] = (int)(part_s[b*PN2 + p] & 0xFFFFFFFFull);

  if (PN < 16 && tid < 16) {
    float sf = (tid + 0.5f) * ((float)PN/16.f) - 0.5f;
    int i0 = (int)floorf(sf) - 1;
    float w[4]; float tot = 0.f;
#pragma unroll
    for (int t = 0; t < 4; ++t) {
      int i = i0 + t;
      float wv = (i >= 0 && i < PN) ? keys_cubic(fabsf(sf - (float)i)) : 0.f;
      w[t] = wv; tot += wv;
    }
    float r = 1.f/tot;
#pragma unroll
    for (int t = 0; t < 4; ++t) W4[tid][t] = w[t]*r;
    I0[tid] = i0;
  }
  __syncthreads();

  // ---- gather codes
  if (PN < 16) {
    for (int e = tid; e < C_*PN2; e += 512) {
      int c = e / PN2, p = e % PN2;
      u.hs[c*PN2 + p] = emb[(size_t)idx_s[p]*32 + c];
    }
  } else {
    for (int e = tid; e < C_*256; e += 512) {
      int c = e >> 8, p = e & 255;
      int y = p >> 4, x = p & 15;
      u.hup[(c*16 + y)*18 + 1 + x] = emb[(size_t)idx_s[p]*32 + c];
    }
    for (int e = tid; e < C_*16; e += 512) { u.hup[e*18] = 0.f; u.hup[e*18 + 17] = 0.f; }
  }
  __syncthreads();

  // ---- separable bicubic upsample PN -> 16
  if (PN < 16) {
    for (int e = tid; e < C_*PN*16; e += 512) {       // x pass
      int jx = e & 15; int rest = e >> 4;
      int iy = rest % PN; int c = rest / PN;
      int i0 = I0[jx];
      float s = 0.f;
#pragma unroll
      for (int t = 0; t < 4; ++t) {
        int ix = i0 + t; int ixc = min(max(ix, 0), PN-1);
        s += W4[jx][t] * u.hs[(c*PN + iy)*PN + ixc];  // w==0 when tap invalid
      }
      tmp_s[(c*PN + iy)*16 + jx] = s;
    }
    __syncthreads();                                   // hs dead from here
    for (int e = tid; e < C_*16; e += 512) { u.hup[e*18] = 0.f; u.hup[e*18 + 17] = 0.f; }
    for (int e = tid; e < C_*256; e += 512) {          // y pass
      int jx = e & 15; int jy = (e >> 4) & 15; int c = e >> 8;
      int i0 = I0[jy];
      float s = 0.f;
#pragma unroll
      for (int t = 0; t < 4; ++t) {
        int iy = i0 + t; int iyc = min(max(iy, 0), PN-1);
        s += W4[jy][t] * tmp_s[(c*PN + iyc)*16 + jx];
      }
      u.hup[(c*16 + jy)*18 + 1 + jx] = s;
    }
    __syncthreads();
  }

  // ---- conv3x3 (zero pad) + blend + updates: thread = (px, co-subgroup of 4)
  const int px = tid & 255;
  const int g  = tid >> 8;               // 0,1
  const int y  = px >> 4, x = px & 15;
  const int co0 = cg*8 + g*4;
  const float* wbase = phi_w + (size_t)co0*32*9;   // [4co][32ci][9], uniform -> s_load
  float acc[4];
#pragma unroll
  for (int o = 0; o < 4; ++o) acc[o] = phi_b[co0 + o];
  for (int ci = 0; ci < 32; ++ci) {
    float wn[9];
#pragma unroll
    for (int ky = 0; ky < 3; ++ky) {
      int yy = y + ky - 1;
      bool v = (yy >= 0 && yy <= 15);
      const float* r = &u.hup[(ci*16 + (v ? yy : 0))*18 + x];  // padded idx x = orig x-1
      wn[ky*3+0] = v ? r[0] : 0.f;
      wn[ky*3+1] = v ? r[1] : 0.f;
      wn[ky*3+2] = v ? r[2] : 0.f;
    }
#pragma unroll
    for (int o = 0; o < 4; ++o) {
      const float* wp = wbase + ((size_t)o*32 + ci)*9;
#pragma unroll
      for (int t = 0; t < 9; ++t) acc[o] = fmaf(wp[t], wn[t], acc[o]);
    }
  }
  float lsum = 0.f;
#pragma unroll
  for (int o = 0; o < 4; ++o) {
    int co = co0 + o;
    float hv = 0.5f*u.hup[(co*16 + y)*18 + 1 + x] + 0.5f*acc[o];
    size_t gi = (((size_t)b*C_ + co)*16 + y)*16 + x;
    float fh = f_hat[gi] + hv;
    f_hat[gi] = fh;
    f_rest[gi] -= hv;
    float dd = fh - f[gi];
    lsum = fmaf(dd, dd, lsum);
  }
  // deterministic block reduction (8 waves)
#pragma unroll
  for (int off = 32; off > 0; off >>= 1) lsum += __shfl_down(lsum, off);
  if ((tid & 63) == 0) wsum[tid >> 6] = lsum;
  __syncthreads();
  if (tid == 0) {
    float s = 0.f;
#pragma unroll
    for (int i = 0; i < 8; ++i) s += wsum[i];
    loss_part[blockIdx.y*64 + blockIdx.x] = s;
  }
}

__global__ void loss_kernel(const float* __restrict__ loss_part, float* __restrict__ out_loss) {
  __shared__ float s[256];
  int t = threadIdx.x;
  float v = 0.f;
#pragma unroll
  for (int i = 0; i < 5; ++i) v += loss_part[i*256 + t];
  s[t] = v;
  __syncthreads();
  for (int off = 128; off > 0; off >>= 1) {
    if (t < off) s[t] += s[t + off];
    __syncthreads();
  }
  if (t == 0) out_loss[0] = s[0] * (1.25f / (5.f * (float)NELEM_));
}

// ---------------------------------------------------------------- launch

extern "C" void kernel_launch(void* const* d_in, const int* in_sizes, int n_in,
                              void* d_out, int out_size, void* d_ws, size_t ws_size,
                              hipStream_t stream) {
  const float* f     = (const float*)d_in[0];
  const float* emb   = (const float*)d_in[1];
  const float* phi_w = (const float*)d_in[2];   // [4][32][32][3][3]
  const float* phi_b = (const float*)d_in[3];   // [4][32]
  float* f_hat    = (float*)d_out;              // [524288]
  float* out_loss = f_hat + NELEM_;             // [1]

  char* ws = (char*)d_ws;
  float* f_rest = (float*)ws;                               // 2 MB
  float* z      = f_rest + NELEM_;                          // 2 MB
  u64*   part   = (u64*)(z + NELEM_);                       // 21824 * 8 B
  float* e_sq   = (float*)(part + NPOS_TOTAL);              // 16 KB
  float* loss_part = e_sq + V_;                             // 5*256 floats

  init_kernel<<<NELEM_/256, 256, 0, stream>>>(f, emb, f_rest, f_hat, e_sq, part, loss_part);

  const int PNs[5]   = {1,2,4,8,16};
  // PHI_IDX from exact float64 replay of np.linspace + np.argmin: [0,1,2,2,3]
  const int PHI[5]   = {0,1,2,2,3};
  const int PBASE[5] = {0, 64, 320, 1344, 5440};

  for (int si = 0; si < 5; ++si) {
    int pn = PNs[si], k = 16/pn, N = B_*pn*pn;
    pool_kernel<<<(N*C_ + 255)/256, 256, 0, stream>>>(f_rest, z, pn, k);
    u64* ps = part + PBASE[si];
    switch (si) {
      case 0: argmin0_kernel<<<64, 256, 0, stream>>>(z, emb, e_sq, ps); break;
      case 1: argmin2_kernel<1,16><<<dim3(1,256), 256, 0, stream>>>(z, emb, e_sq, ps, 16); break;
      case 2: argmin2_kernel<1,64><<<dim3(4,64),  256, 0, stream>>>(z, emb, e_sq, ps, 64); break;
      case 3: argmin2_kernel<2,64><<<dim3(8,64),  256, 0, stream>>>(z, emb, e_sq, ps, 64); break;
      case 4: argmin2_kernel<2,64><<<dim3(32,32), 256, 0, stream>>>(z, emb, e_sq, ps, 128); break;
    }
    const float* pw = phi_w + (size_t)PHI[si]*32*32*9;
    const float* pb = phi_b + (size_t)PHI[si]*32;
    dim3 cgrid(B_, 4);
    float* lp = loss_part + si*256;
    switch (pn) {
      case 1:  upconv_kernel<1 ><<<cgrid,512,0,stream>>>(ps, emb, pw, pb, f, f_hat, f_rest, lp); break;
      case 2:  upconv_kernel<2 ><<<cgrid,512,0,stream>>>(ps, emb, pw, pb, f, f_hat, f_rest, lp); break;
      case 4:  upconv_kernel<4 ><<<cgrid,512,0,stream>>>(ps, emb, pw, pb, f, f_hat, f_rest, lp); break;
      case 8:  upconv_kernel<8 ><<<cgrid,512,0,stream>>>(ps, emb, pw, pb, f, f_hat, f_rest, lp); break;
      case 16: upconv_kernel<16><<<cgrid,512,0,stream>>>(ps, emb, pw, pb, f, f_hat, f_rest, lp); break;
    }
  }
  loss_kernel<<<1, 256, 0, stream>>>(loss_part, out_loss);
}

// Round 5
// 240.152 us; speedup vs baseline: 1.5061x; 1.1277x over previous
//
#include <hip/hip_runtime.h>

typedef unsigned long long u64;

#define B_ 64
#define C_ 32
#define H_ 16
#define W_ 16
#define V_ 4096
#define NELEM_ (B_*C_*H_*W_)   // 524288
#define NPOS_TOTAL 21824       // 64*(1+4+16+64+256)

// ---------------------------------------------------------------- utilities

__device__ __forceinline__ float keys_cubic(float x) {
  // Keys cubic kernel, a = -0.5 (jax.image.resize 'cubic'), x >= 0
  if (x >= 2.f) return 0.f;
  if (x >= 1.f) return ((-0.5f*x + 2.5f)*x - 4.f)*x + 2.f;
  return (1.5f*x - 2.5f)*x*x + 1.f;
}

__device__ __forceinline__ u64 pack_key(float d, int idx) {
  unsigned bu = __float_as_uint(d);
  unsigned m = bu ^ ((bu >> 31) ? 0xFFFFFFFFu : 0x80000000u);  // order-preserving
  return ((u64)m << 32) | (unsigned)idx;
}

// ------------------------------------------------- setup: e_sq, part, pool0

__global__ void setup_kernel(const float* __restrict__ f, const float* __restrict__ emb,
                             float* __restrict__ e_sq, u64* __restrict__ part,
                             float* __restrict__ z0) {
  int i = blockIdx.x*blockDim.x + threadIdx.x;
  if (i < NPOS_TOTAL) part[i] = ~0ull;
  if (i < V_) {
    const float4* p = (const float4*)(emb + (size_t)i*32);
    float s = 0.f;
#pragma unroll
    for (int j = 0; j < 8; ++j) { float4 q = p[j]; s += q.x*q.x + q.y*q.y + q.z*q.z + q.w*q.w; }
    e_sq[i] = s;
  }
  if (i < B_*C_) {   // pool0: z0[b][c] = mean of f[b][c][:][:]  (2048 threads)
    const float4* p = (const float4*)(f + (size_t)i*256);
    float s = 0.f;
    for (int j = 0; j < 64; ++j) { float4 q = p[j]; s += (q.x + q.y) + (q.z + q.w); }
    z0[i] = s * (1.f/256.f);
  }
}

// ---------------------------------------------------------------- argmin

// each thread owns P positions; codes staged in LDS tiles; atomicMin reduce.
template<int P, int TILE>
__global__ void __launch_bounds__(256, 2) argmin2_kernel(
    const float* __restrict__ z, const float* __restrict__ emb,
    const float* __restrict__ e_sq, u64* __restrict__ part, int cpc) {
  __shared__ float cl[TILE*32];
  __shared__ float es[TILE];
  const int tid = threadIdx.x;
  const int n0 = blockIdx.x*(256*P) + tid;
  float zb[P][32]; float zz[P];
#pragma unroll
  for (int p = 0; p < P; ++p) {
    const float4* zp = (const float4*)(z + (size_t)(n0 + p*256)*32);
#pragma unroll
    for (int i = 0; i < 8; ++i) {
      float4 q = zp[i];
      zb[p][4*i+0]=q.x; zb[p][4*i+1]=q.y; zb[p][4*i+2]=q.z; zb[p][4*i+3]=q.w;
    }
    float s = 0.f;
#pragma unroll
    for (int i = 0; i < 32; ++i) s = fmaf(zb[p][i], zb[p][i], s);
    zz[p] = s;
  }
  const int v0 = blockIdx.y * cpc;
  float bd[P]; int bi[P];
#pragma unroll
  for (int p = 0; p < P; ++p) { bd[p] = 3.4e38f; bi[p] = v0; }
  for (int t0 = 0; t0 < cpc; t0 += TILE) {
    __syncthreads();
    const float4* src = (const float4*)(emb + (size_t)(v0 + t0)*32);
    for (int e = tid; e < TILE*8; e += 256) ((float4*)cl)[e] = src[e];
    if (tid < TILE) es[tid] = e_sq[v0 + t0 + tid];
    __syncthreads();
#pragma unroll 2
    for (int c = 0; c < TILE; ++c) {
      const float4* cp = (const float4*)(cl + c*32);
      float4 q[8];
#pragma unroll
      for (int i = 0; i < 8; ++i) q[i] = cp[i];
      float ev = es[c];
#pragma unroll
      for (int p = 0; p < P; ++p) {
        float a0=0.f, a1=0.f, a2=0.f, a3=0.f;
#pragma unroll
        for (int i = 0; i < 8; ++i) {
          a0 = fmaf(zb[p][4*i+0], q[i].x, a0);
          a1 = fmaf(zb[p][4*i+1], q[i].y, a1);
          a2 = fmaf(zb[p][4*i+2], q[i].z, a2);
          a3 = fmaf(zb[p][4*i+3], q[i].w, a3);
        }
        float dot = (a0+a1)+(a2+a3);
        float d = (zz[p] + ev) - 2.f*dot;
        bool lt = d < bd[p];
        bd[p] = lt ? d : bd[p];
        bi[p] = lt ? (v0 + t0 + c) : bi[p];
      }
    }
  }
#pragma unroll
  for (int p = 0; p < P; ++p)
    atomicMin(part + n0 + p*256, pack_key(bd[p], bi[p]));
}

// si=0 special: 64 positions, block = 64-code chunk, 4 sub-chunks of 16
__global__ void __launch_bounds__(256) argmin0_kernel(
    const float* __restrict__ z, const float* __restrict__ emb,
    const float* __restrict__ e_sq, u64* __restrict__ part) {
  __shared__ float cl[64*32];
  __shared__ float es[64];
  const int tid = threadIdx.x;
  const int v0 = blockIdx.x * 64;
  const float4* src = (const float4*)(emb + (size_t)v0*32);
  for (int e = tid; e < 64*8; e += 256) ((float4*)cl)[e] = src[e];
  if (tid < 64) es[tid] = e_sq[v0 + tid];
  __syncthreads();
  const int p = tid & 63, sub = tid >> 6;
  float zb[32];
  const float4* zp = (const float4*)(z + (size_t)p*32);
#pragma unroll
  for (int i = 0; i < 8; ++i) {
    float4 q = zp[i];
    zb[4*i+0]=q.x; zb[4*i+1]=q.y; zb[4*i+2]=q.z; zb[4*i+3]=q.w;
  }
  float zz = 0.f;
#pragma unroll
  for (int i = 0; i < 32; ++i) zz = fmaf(zb[i], zb[i], zz);
  float bd = 3.4e38f; int bi = v0;
  for (int c = sub*16; c < sub*16 + 16; ++c) {
    const float4* cp = (const float4*)(cl + c*32);
    float4 q[8];
#pragma unroll
    for (int i = 0; i < 8; ++i) q[i] = cp[i];
    float a0=0.f, a1=0.f, a2=0.f, a3=0.f;
#pragma unroll
    for (int i = 0; i < 8; ++i) {
      a0 = fmaf(zb[4*i+0], q[i].x, a0);
      a1 = fmaf(zb[4*i+1], q[i].y, a1);
      a2 = fmaf(zb[4*i+2], q[i].z, a2);
      a3 = fmaf(zb[4*i+3], q[i].w, a3);
    }
    float dot = (a0+a1)+(a2+a3);
    float d = (zz + es[c]) - 2.f*dot;
    if (d < bd) { bd = d; bi = v0 + c; }
  }
  atomicMin(part + p, pack_key(bd, bi));
}

// ---------------------------------------------------------------- fused upconv

// grid (64 images, 4 co-groups), 512 threads.
// idx read -> gather -> bicubic upsample -> conv3x3 blend -> f_hat/f_rest update
// -> pooled z for NEXT scale (this block's 8 channels) -> loss partial.
template<int PN, int NEXT_PN, bool FIRST>
__global__ void __launch_bounds__(512) upconv_kernel(
    const u64* __restrict__ part_s,
    const float* __restrict__ emb,
    const float* __restrict__ phi_w,   // [32][32][3][3] (offset by phi idx)
    const float* __restrict__ phi_b,   // [32]
    const float* __restrict__ f,
    float* __restrict__ f_hat,
    float* __restrict__ f_rest,
    float* __restrict__ z_next,
    float* __restrict__ loss_part)
{
  constexpr int PN2 = PN*PN;
  constexpr bool POOLED = (NEXT_PN != 0 && NEXT_PN < 16);
  const int b = blockIdx.x;
  const int cg = blockIdx.y;
  const int tid = threadIdx.x;

  __shared__ int   idx_s[PN2];
  __shared__ float W4[16][4];
  __shared__ int   I0[16];
  __shared__ float tmp_s[(PN < 16) ? C_*PN*16 : 1];
  __shared__ float pool_s[POOLED ? 8*256 : 1];
  union HupHs { float hup[C_*16*18]; float hs[C_*16*18]; };  // hup row: [16 + 2 pad]
  __shared__ HupHs u;
  __shared__ float wsum[8];

  for (int p = tid; p < PN2; p += 512)
    idx_s[p] = (int)(part_s[b*PN2 + p] & 0xFFFFFFFFull);

  if (PN < 16 && tid < 16) {
    float sf = (tid + 0.5f) * ((float)PN/16.f) - 0.5f;
    int i0 = (int)floorf(sf) - 1;
    float w[4]; float tot = 0.f;
#pragma unroll
    for (int t = 0; t < 4; ++t) {
      int i = i0 + t;
      float wv = (i >= 0 && i < PN) ? keys_cubic(fabsf(sf - (float)i)) : 0.f;
      w[t] = wv; tot += wv;
    }
    float r = 1.f/tot;
#pragma unroll
    for (int t = 0; t < 4; ++t) W4[tid][t] = w[t]*r;
    I0[tid] = i0;
  }
  __syncthreads();

  // ---- gather codes
  if (PN < 16) {
    for (int e = tid; e < C_*PN2; e += 512) {
      int c = e / PN2, p = e % PN2;
      u.hs[c*PN2 + p] = emb[(size_t)idx_s[p]*32 + c];
    }
  } else {
    for (int e = tid; e < C_*256; e += 512) {
      int c = e >> 8, p = e & 255;
      int y = p >> 4, x = p & 15;
      u.hup[(c*16 + y)*18 + 1 + x] = emb[(size_t)idx_s[p]*32 + c];
    }
    for (int e = tid; e < C_*16; e += 512) { u.hup[e*18] = 0.f; u.hup[e*18 + 17] = 0.f; }
  }
  __syncthreads();

  // ---- separable bicubic upsample PN -> 16
  if (PN < 16) {
    for (int e = tid; e < C_*PN*16; e += 512) {       // x pass
      int jx = e & 15; int rest = e >> 4;
      int iy = rest % PN; int c = rest / PN;
      int i0 = I0[jx];
      float s = 0.f;
#pragma unroll
      for (int t = 0; t < 4; ++t) {
        int ix = i0 + t; int ixc = min(max(ix, 0), PN-1);
        s += W4[jx][t] * u.hs[(c*PN + iy)*PN + ixc];  // w==0 when tap invalid
      }
      tmp_s[(c*PN + iy)*16 + jx] = s;
    }
    __syncthreads();                                   // hs dead from here
    for (int e = tid; e < C_*16; e += 512) { u.hup[e*18] = 0.f; u.hup[e*18 + 17] = 0.f; }
    for (int e = tid; e < C_*256; e += 512) {          // y pass
      int jx = e & 15; int jy = (e >> 4) & 15; int c = e >> 8;
      int i0 = I0[jy];
      float s = 0.f;
#pragma unroll
      for (int t = 0; t < 4; ++t) {
        int iy = i0 + t; int iyc = min(max(iy, 0), PN-1);
        s += W4[jy][t] * tmp_s[(c*PN + iyc)*16 + jx];
      }
      u.hup[(c*16 + jy)*18 + 1 + jx] = s;
    }
    __syncthreads();
  }

  // ---- conv3x3 (zero pad) + blend: thread = (px, co-subgroup of 4)
  const int px = tid & 255;
  const int g  = tid >> 8;               // 0,1
  const int y  = px >> 4, x = px & 15;
  const int co0 = cg*8 + g*4;
  const float* wbase = phi_w + (size_t)co0*32*9;   // wave-uniform -> scalar loads
  float acc[4];
#pragma unroll
  for (int o = 0; o < 4; ++o) acc[o] = phi_b[co0 + o];
  for (int ci = 0; ci < 32; ++ci) {
    float wn[9];
#pragma unroll
    for (int ky = 0; ky < 3; ++ky) {
      int yy = y + ky - 1;
      bool v = (yy >= 0 && yy <= 15);
      const float* r = &u.hup[(ci*16 + (v ? yy : 0))*18 + x];  // padded idx x = orig x-1
      wn[ky*3+0] = v ? r[0] : 0.f;
      wn[ky*3+1] = v ? r[1] : 0.f;
      wn[ky*3+2] = v ? r[2] : 0.f;
    }
#pragma unroll
    for (int o = 0; o < 4; ++o) {
      const float* wp = wbase + ((size_t)o*32 + ci)*9;
#pragma unroll
      for (int t = 0; t < 9; ++t) acc[o] = fmaf(wp[t], wn[t], acc[o]);
    }
  }

  // ---- updates + next-scale pooled z + loss
  float lsum = 0.f;
#pragma unroll
  for (int o = 0; o < 4; ++o) {
    int co = co0 + o;
    float hv = 0.5f*u.hup[(co*16 + y)*18 + 1 + x] + 0.5f*acc[o];
    size_t gi = (((size_t)b*C_ + co)*16 + y)*16 + x;
    float fv = f[gi];
    float fh = FIRST ? hv : (f_hat[gi] + hv);
    f_hat[gi] = fh;
    if constexpr (NEXT_PN != 0) {
      float nfr = FIRST ? (fv - hv) : (f_rest[gi] - hv);
      f_rest[gi] = nfr;
      if constexpr (NEXT_PN == 16) {
        z_next[((size_t)b*256 + px)*32 + co] = nfr;
      } else {
        pool_s[(g*4 + o)*256 + px] = nfr;
      }
    }
    float dd = fh - fv;
    lsum = fmaf(dd, dd, lsum);
  }
  if constexpr (POOLED) {
    constexpr int NP = (NEXT_PN > 0) ? NEXT_PN : 1;
    constexpr int NP2 = NP*NP;
    constexpr int KP = 16/NP;
    __syncthreads();
    if (tid < 8*NP2) {
      int c_l = tid / NP2, p = tid % NP2;
      int yy = (p / NP)*KP, xx = (p % NP)*KP;
      float s = 0.f;
      for (int a = 0; a < KP; ++a)
        for (int e = 0; e < KP; ++e)
          s += pool_s[c_l*256 + (yy + a)*16 + xx + e];
      z_next[((size_t)b*NP2 + p)*32 + cg*8 + c_l] = s * (1.f/(float)(KP*KP));
    }
  }
  // deterministic block loss reduction (8 waves)
#pragma unroll
  for (int off = 32; off > 0; off >>= 1) lsum += __shfl_down(lsum, off);
  if ((tid & 63) == 0) wsum[tid >> 6] = lsum;
  __syncthreads();
  if (tid == 0) {
    float s = 0.f;
#pragma unroll
    for (int i = 0; i < 8; ++i) s += wsum[i];
    loss_part[blockIdx.y*64 + blockIdx.x] = s;
  }
}

__global__ void loss_kernel(const float* __restrict__ loss_part, float* __restrict__ out_loss) {
  __shared__ float s[256];
  int t = threadIdx.x;
  float v = 0.f;
#pragma unroll
  for (int i = 0; i < 5; ++i) v += loss_part[i*256 + t];
  s[t] = v;
  __syncthreads();
  for (int off = 128; off > 0; off >>= 1) {
    if (t < off) s[t] += s[t + off];
    __syncthreads();
  }
  if (t == 0) out_loss[0] = s[0] * (1.25f / (5.f * (float)NELEM_));
}

// ---------------------------------------------------------------- launch

extern "C" void kernel_launch(void* const* d_in, const int* in_sizes, int n_in,
                              void* d_out, int out_size, void* d_ws, size_t ws_size,
                              hipStream_t stream) {
  const float* f     = (const float*)d_in[0];
  const float* emb   = (const float*)d_in[1];
  const float* phi_w = (const float*)d_in[2];   // [4][32][32][3][3]
  const float* phi_b = (const float*)d_in[3];   // [4][32]
  float* f_hat    = (float*)d_out;              // [524288]
  float* out_loss = f_hat + NELEM_;             // [1]

  char* ws = (char*)d_ws;
  float* f_rest = (float*)ws;                               // 2 MB
  float* z      = f_rest + NELEM_;                          // 2 MB
  u64*   part   = (u64*)(z + NELEM_);                       // 21824 * 8 B
  float* e_sq   = (float*)(part + NPOS_TOTAL);              // 16 KB
  float* loss_part = e_sq + V_;                             // 5*256 floats

  // PHI_IDX from exact float64 replay of np.linspace + np.argmin: [0,1,2,2,3]
  const float* pw0 = phi_w;                 const float* pb0 = phi_b;
  const float* pw1 = phi_w + 1*32*32*9;     const float* pb1 = phi_b + 1*32;
  const float* pw2 = phi_w + 2*32*32*9;     const float* pb2 = phi_b + 2*32;
  const float* pw3 = phi_w + 3*32*32*9;     const float* pb3 = phi_b + 3*32;

  setup_kernel<<<(NPOS_TOTAL + 255)/256, 256, 0, stream>>>(f, emb, e_sq, part, z);

  dim3 cgrid(B_, 4);
  // si=0 (pn=1)
  argmin0_kernel<<<64, 256, 0, stream>>>(z, emb, e_sq, part + 0);
  upconv_kernel<1, 2, true><<<cgrid, 512, 0, stream>>>(part + 0, emb, pw0, pb0,
      f, f_hat, f_rest, z, loss_part + 0*256);
  // si=1 (pn=2): N=256
  argmin2_kernel<1,16><<<dim3(1,256), 256, 0, stream>>>(z, emb, e_sq, part + 64, 16);
  upconv_kernel<2, 4, false><<<cgrid, 512, 0, stream>>>(part + 64, emb, pw1, pb1,
      f, f_hat, f_rest, z, loss_part + 1*256);
  // si=2 (pn=4): N=1024
  argmin2_kernel<2,32><<<dim3(2,128), 256, 0, stream>>>(z, emb, e_sq, part + 320, 32);
  upconv_kernel<4, 8, false><<<cgrid, 512, 0, stream>>>(part + 320, emb, pw2, pb2,
      f, f_hat, f_rest, z, loss_part + 2*256);
  // si=3 (pn=8): N=4096
  argmin2_kernel<4,64><<<dim3(4,64), 256, 0, stream>>>(z, emb, e_sq, part + 1344, 64);
  upconv_kernel<8, 16, false><<<cgrid, 512, 0, stream>>>(part + 1344, emb, pw2, pb2,
      f, f_hat, f_rest, z, loss_part + 3*256);
  // si=4 (pn=16): N=16384
  argmin2_kernel<4,64><<<dim3(16,32), 256, 0, stream>>>(z, emb, e_sq, part + 5440, 128);
  upconv_kernel<16, 0, false><<<cgrid, 512, 0, stream>>>(part + 5440, emb, pw3, pb3,
      f, f_hat, f_rest, z, loss_part + 4*256);

  loss_kernel<<<1, 256, 0, stream>>>(loss_part, out_loss);
}